// Round 4
// baseline (444.190 us; speedup 1.0000x reference)
//
#include <hip/hip_runtime.h>
#include <math.h>

#define NB 16
#define NC 64
#define HW 160
#define PLANE (HW * HW)               // 25600
#define SG 161                         // site grid (H+1)
#define NSITES (NB * SG * SG)          // 414736
#define NCONVBLK ((NSITES + 63) / 64)  // 6481
#define CHUNK ((NCONVBLK + 7) / 8)     // 811 site-blocks per XCD
#define PADBLK (8 * CHUNK)             // 6488
#define OUT_LD_OFF (NB * NC * PLANE)   // logdet output offset

// Map local submatrix index -> channel index for the INDS masks.
__device__ inline int chmap(int i, int n, int pa, int pb) {
    if (n == 64) return i;
    if (n == 32) return ((i >> 1) << 2) | ((i & 1) ? pb : pa);
    return (i << 2) | pa;
}

__device__ inline void wave_argmax(float& cand, int& idx) {
    for (int off = 32; off; off >>= 1) {
        float oc = __shfl_down(cand, off, 64);
        int oi = __shfl_down(idx, off, 64);
        if (oc > cand) { cand = oc; idx = oi; }
    }
    idx = __shfl(idx, 0, 64);
}

// Single-wave LU, lane = COLUMN, row stride st = n+1 (odd -> column reads
// bank-conflict-free). Row updates at each k are independent across rows ->
// the LDS read/fma/write per row pipelines instead of chaining latency.
__device__ float wave_lu(const float* __restrict__ W, float* A, int n, int sh,
                         int st, int pa, int pb, int lane) {
    for (int e = lane; e < n * n; e += 64) {
        int i = e >> sh, j = e & (n - 1);
        A[i * st + j] = W[chmap(i, n, pa, pb) * 64 + chmap(j, n, pa, pb)];
    }
    asm volatile("s_waitcnt lgkmcnt(0) vmcnt(0)" ::: "memory");
    float logdet = 0.f;
    bool colact = lane < n;
    for (int k = 0; k < n; ++k) {
        float cand = -1.f;
        int idx = k;
        if (lane >= k && lane < n) { cand = fabsf(A[lane * st + k]); idx = lane; }
        wave_argmax(cand, idx);
        int p = idx;
        float pr = 0.f;
        if (colact) {
            float tk = A[k * st + lane], tp = A[p * st + lane];
            if (p != k) { A[k * st + lane] = tp; A[p * st + lane] = tk; }
            pr = (p != k) ? tp : tk;  // post-swap row-k element at column `lane`
        }
        asm volatile("s_waitcnt lgkmcnt(0)" ::: "memory");
        float pivv = __shfl(pr, k, 64);
        logdet += logf(fabsf(pivv));
        float rpiv = 1.f / pivv;
        for (int i = k + 1; i < n; ++i) {
            float aik = A[i * st + k];  // broadcast read (precedes this row's write)
            float mult = aik * rpiv;
            if (colact) A[i * st + lane] = fmaf(-mult, pr, A[i * st + lane]);
        }
        asm volatile("s_waitcnt lgkmcnt(0)" ::: "memory");
    }
    return logdet;
}

// 4-wave LU of the full 64x64 W. lane = column, stride 65; rows strided
// across waves each step. Returns log|det| (valid in wave 0).
__device__ float block_lu64(const float* __restrict__ W, float* A, float* comm,
                            int wid, int lane) {
    int tid = wid * 64 + lane;
    for (int e = tid; e < 64 * 64; e += 256) A[(e >> 6) * 65 + (e & 63)] = W[e];
    __syncthreads();
    float logdet = 0.f;
    for (int k = 0; k < 64; ++k) {
        if (wid == 0) {
            float cand = -1.f;
            int idx = k;
            if (lane >= k) { cand = fabsf(A[lane * 65 + k]); idx = lane; }
            wave_argmax(cand, idx);
            int p = idx;
            float tk = A[k * 65 + lane], tp = A[p * 65 + lane];
            if (p != k) { A[k * 65 + lane] = tp; A[p * 65 + lane] = tk; }
            float prk = (p != k) ? tp : tk;
            float pivv = __shfl(prk, k, 64);
            logdet += logf(fabsf(pivv));
            if (lane == 0) comm[0] = 1.f / pivv;
        }
        __syncthreads();  // publish swap + rpiv
        float rpiv = comm[0];
        float pr = A[k * 65 + lane];
        int i0 = (k + 1) + ((wid - (k + 1)) & 3);
        for (int i = i0; i < 64; i += 4) {
            float aik = A[i * 65 + k];  // broadcast
            float mult = aik * rpiv;
            A[i * 65 + lane] = fmaf(-mult, pr, A[i * 65 + lane]);
        }
        __syncthreads();  // updates done before next pivot search
    }
    return logdet;
}

__global__ __launch_bounds__(256, 8) void InvConv1x1GridAlign_kernel(
    const float* __restrict__ x, const float* __restrict__ ld_in,
    const float* __restrict__ W, float* __restrict__ out) {
    // Union: det block uses S as LU64 (64x65=4160) then 4 strips of 32x33=1056;
    // conv blocks use S[0..4096) as the v-tile [channel][site].
    __shared__ float S[4 * 32 * 33];  // 4224 floats = 16.9 KB
    __shared__ float comm[1];
    __shared__ float partial[4];

    int wid = threadIdx.x >> 6;
    int l = threadIdx.x & 63;

    if (blockIdx.x == 0) {
        // ---- determinant block: LU64 on 4 waves, then per-wave 32s & 16s ----
        float ld64 = block_lu64(W, S, comm, wid, l);
        __syncthreads();
        float* strip = S + wid * 1056;
        float part;
        if (wid == 0) {
            part = 25281.f * ld64 + 159.f * wave_lu(W, strip, 32, 5, 33, 2, 3, l)
                 + wave_lu(W, strip, 16, 4, 17, 3, 0, l);  // t + tl
        } else if (wid == 1) {
            part = 159.f * wave_lu(W, strip, 32, 5, 33, 0, 1, l)
                 + wave_lu(W, strip, 16, 4, 17, 2, 0, l);  // b + tr
        } else if (wid == 2) {
            part = 159.f * wave_lu(W, strip, 32, 5, 33, 1, 3, l)
                 + wave_lu(W, strip, 16, 4, 17, 1, 0, l);  // l + bl
        } else {
            part = 159.f * wave_lu(W, strip, 32, 5, 33, 0, 2, l)
                 + wave_lu(W, strip, 16, 4, 17, 0, 0, l);  // r + br
        }
        if (l == 0) partial[wid] = part;
        __syncthreads();
        if (threadIdx.x < NB) {
            float dl = partial[0] + partial[1] + partial[2] + partial[3];
            out[OUT_LD_OFF + threadIdx.x] = ld_in[threadIdx.x] + dl;
        }
        return;
    }

    // ---- conv blocks: XCD swizzle keeps consecutive site-blocks on one XCD
    //      so shared output cache lines merge in a single L2. ----
    int b0 = blockIdx.x - 1;
    int sb = (b0 & 7) * CHUNK + (b0 >> 3);
    if (sb >= NCONVBLK) return;  // uniform per block; before any __syncthreads

    int s = sb * 64 + l;
    bool live = s < NSITES;
    int sc = live ? s : 0;
    unsigned us = (unsigned)sc;
    unsigned bb = us / (SG * SG);
    unsigned rr = us - bb * (SG * SG);
    unsigned uy = rr / SG;
    int Y = (int)uy;
    int X = (int)(rr - uy * SG);

    const float* xb = x + (size_t)bb * NC * PLANE;
    float* ob = out + (size_t)bb * NC * PLANE;

    bool okT = (Y >= 1), okB = (Y <= HW - 1), okL = (X >= 1), okR = (X <= HW - 1);
    bool v00 = live && okT && okL, v01 = live && okT && okR;
    bool v10 = live && okB && okL, v11 = live && okB && okR;
    int off00 = (Y - 1) * HW + (X - 1);
    int off01 = (Y - 1) * HW + X;
    int off10 = Y * HW + (X - 1);
    int off11 = Y * HW + X;

    // Phase 1: gather channels c = 16w+4g+m (m literal) into S[c][site].
    {
        const float* xw = xb + (size_t)wid * 16 * PLANE;
        float* Arow = S + wid * 16 * 64 + l;
#pragma unroll
        for (int g = 0; g < 4; ++g) {
            const float* pg = xw + (size_t)g * 4 * PLANE;
            Arow[(g * 4 + 0) * 64] = v00 ? pg[3 * PLANE + off00] : 0.f;
            Arow[(g * 4 + 1) * 64] = v01 ? pg[2 * PLANE + off01] : 0.f;
            Arow[(g * 4 + 2) * 64] = v10 ? pg[1 * PLANE + off10] : 0.f;
            Arow[(g * 4 + 3) * 64] = v11 ? pg[0 * PLANE + off11] : 0.f;
        }
    }
    __syncthreads();

    // Phase 2: u[j] = sum_c W[16w+j][c] * v[c]; W rows wave-uniform -> s_load.
    int wu = __builtin_amdgcn_readfirstlane(wid);
    const float* Wbase = W + (size_t)wu * 16 * 64;
    float u[16];
#pragma unroll
    for (int j = 0; j < 16; ++j) u[j] = 0.f;

#pragma unroll
    for (int cb = 0; cb < 4; ++cb) {
        float v[16];
#pragma unroll
        for (int i = 0; i < 16; ++i) v[i] = S[(cb * 16 + i) * 64 + l];
#pragma unroll
        for (int j = 0; j < 16; ++j) {
            const float* wr = Wbase + j * 64 + cb * 16;
            float a = u[j];
#pragma unroll
            for (int k = 0; k < 16; ++k) a = fmaf(wr[k], v[k], a);
            u[j] = a;
        }
    }

    // Phase 3: scatter u[j] (o = 16w+4g+m) -> plane o^3, quadrant m literal.
    {
        float* ow = ob + (size_t)wid * 16 * PLANE;
#pragma unroll
        for (int g = 0; g < 4; ++g) {
            float* pg = ow + (size_t)g * 4 * PLANE;
            if (v00) pg[3 * PLANE + off00] = u[g * 4 + 0];
            if (v01) pg[2 * PLANE + off01] = u[g * 4 + 1];
            if (v10) pg[1 * PLANE + off10] = u[g * 4 + 2];
            if (v11) pg[0 * PLANE + off11] = u[g * 4 + 3];
        }
    }
}

extern "C" void kernel_launch(void* const* d_in, const int* in_sizes, int n_in,
                              void* d_out, int out_size, void* d_ws, size_t ws_size,
                              hipStream_t stream) {
    const float* x = (const float*)d_in[0];
    const float* ld = (const float*)d_in[1];
    const float* W = (const float*)d_in[2];
    float* out = (float*)d_out;
    hipLaunchKernelGGL(InvConv1x1GridAlign_kernel, dim3(PADBLK + 1), dim3(256), 0,
                       stream, x, ld, W, out);
}